// Round 3
// baseline (2389.815 us; speedup 1.0000x reference)
//
#include <hip/hip_runtime.h>

#define HDIM 64
#define BATCH 256
#define TLEN 2048
#define CH 16   // layer-2 streaming chunk (steps)

__device__ __forceinline__ float rcp_fast(float x) { return __builtin_amdgcn_rcpf(x); }
__device__ __forceinline__ float sigmoid_fast(float x) { return rcp_fast(1.0f + __expf(-x)); }
__device__ __forceinline__ float tanh_fast(float x)    { return 1.0f - 2.0f * rcp_fast(1.0f + __expf(2.0f * x)); }

// quad_perm DPP adds: lane^1 and lane^2 (VALU, no LDS pipe)
__device__ __forceinline__ float dpp_xor1_add(float x) {
    int v = __builtin_amdgcn_update_dpp(0, __float_as_int(x), 0xB1, 0xF, 0xF, true);
    return x + __int_as_float(v);
}
__device__ __forceinline__ float dpp_xor2_add(float x) {
    int v = __builtin_amdgcn_update_dpp(0, __float_as_int(x), 0x4E, 0xF, 0xF, true);
    return x + __int_as_float(v);
}
__device__ __forceinline__ float swz_xor4_add(float x) {
    int v = __builtin_amdgcn_ds_swizzle(__float_as_int(x), 0x101F); // xor-4 butterfly
    return x + __int_as_float(v);
}
__device__ __forceinline__ float dot4(float4 a, float4 b, float acc) {
    acc = fmaf(a.x, b.x, acc); acc = fmaf(a.y, b.y, acc);
    acc = fmaf(a.z, b.z, acc); acc = fmaf(a.w, b.w, acc);
    return acc;
}

// Force a float4 to live in VGPRs: the empty asm "redefines" the value so the
// compiler cannot rematerialize the originating global load inside the loop.
#define PIN4(v) asm volatile("" : "+v"((v).x), "+v"((v).y), "+v"((v).z), "+v"((v).w))
#define PIN1(v) asm volatile("" : "+v"(v))

// ---------------- Layer 1: bidirectional, input dim 4 ----------------
// grid = 2*BATCH blocks, 256 threads. Quad owns unit u = tid>>2; lane p = tid&3
// owns k-slice of 16. Weights pinned in registers, quad-DPP reduce.
__global__ __launch_bounds__(256, 2)
void lstm_layer1(const float* __restrict__ x,      // [B,T,4]
                 const float* __restrict__ Wih_f, const float* __restrict__ Whh_f, const float* __restrict__ b_f,
                 const float* __restrict__ Wih_b, const float* __restrict__ Whh_b, const float* __restrict__ b_b,
                 float* __restrict__ out1)         // [B,T,2H]
{
    const int bidx = blockIdx.x >> 1;
    const int dir  = blockIdx.x & 1;
    const float* __restrict__ Wih = dir ? Wih_b : Wih_f;
    const float* __restrict__ Whh = dir ? Whh_b : Whh_f;
    const float* __restrict__ bb  = dir ? b_b   : b_f;

    const int tid = threadIdx.x;
    const int u   = tid >> 2;
    const int p   = tid & 3;

    __shared__ float xlds[TLEN * 4];    // 32 KB
    __shared__ float hbuf[2][HDIM];

    {   // preload x[b] (2048 float4)
        const float4* src = (const float4*)(x + (size_t)bidx * TLEN * 4);
        float4* dst = (float4*)xlds;
        #pragma unroll
        for (int i = 0; i < 8; ++i) dst[tid + 256 * i] = src[tid + 256 * i];
    }
    if (tid < 2 * HDIM) ((float*)hbuf)[tid] = 0.f;

    // recurrent weights: row gi*64+u, cols [16p,16p+16)
    const float* wbase = Whh + (size_t)u * HDIM + 16 * p;
    float4 W00 = *(const float4*)(wbase + 0*4096 +  0), W01 = *(const float4*)(wbase + 0*4096 +  4),
           W02 = *(const float4*)(wbase + 0*4096 +  8), W03 = *(const float4*)(wbase + 0*4096 + 12);
    float4 W10 = *(const float4*)(wbase + 1*4096 +  0), W11 = *(const float4*)(wbase + 1*4096 +  4),
           W12 = *(const float4*)(wbase + 1*4096 +  8), W13 = *(const float4*)(wbase + 1*4096 + 12);
    float4 W20 = *(const float4*)(wbase + 2*4096 +  0), W21 = *(const float4*)(wbase + 2*4096 +  4),
           W22 = *(const float4*)(wbase + 2*4096 +  8), W23 = *(const float4*)(wbase + 2*4096 + 12);
    float4 W30 = *(const float4*)(wbase + 3*4096 +  0), W31 = *(const float4*)(wbase + 3*4096 +  4),
           W32 = *(const float4*)(wbase + 3*4096 +  8), W33 = *(const float4*)(wbase + 3*4096 + 12);
    float4 I0 = *(const float4*)(Wih + (0*64 + u) * 4);
    float4 I1 = *(const float4*)(Wih + (1*64 + u) * 4);
    float4 I2 = *(const float4*)(Wih + (2*64 + u) * 4);
    float4 I3 = *(const float4*)(Wih + (3*64 + u) * 4);
    float b0 = bb[u], b1 = bb[64 + u], b2g = bb[128 + u], b3 = bb[192 + u];
    PIN4(W00); PIN4(W01); PIN4(W02); PIN4(W03);
    PIN4(W10); PIN4(W11); PIN4(W12); PIN4(W13);
    PIN4(W20); PIN4(W21); PIN4(W22); PIN4(W23);
    PIN4(W30); PIN4(W31); PIN4(W32); PIN4(W33);
    PIN4(I0); PIN4(I1); PIN4(I2); PIN4(I3);
    PIN1(b0); PIN1(b1); PIN1(b2g); PIN1(b3);
    __syncthreads();

    float c = 0.f;
    const float* xp = xlds + (dir ? (TLEN - 1) * 4 : 0);
    const int xstep = dir ? -4 : 4;
    float* outp = out1 + (size_t)bidx * TLEN * (2 * HDIM)
                + (size_t)(dir ? (TLEN - 1) : 0) * (2 * HDIM) + dir * HDIM + u;
    const ptrdiff_t ostep = dir ? -(2 * HDIM) : (2 * HDIM);

    #pragma unroll 2
    for (int s = 0; s < TLEN; ++s) {
        const float* hb = hbuf[s & 1];
        const float4 h0 = *(const float4*)(hb + 16 * p + 0);
        const float4 h1 = *(const float4*)(hb + 16 * p + 4);
        const float4 h2 = *(const float4*)(hb + 16 * p + 8);
        const float4 h3 = *(const float4*)(hb + 16 * p + 12);

        float g0 = dot4(W03, h3, dot4(W02, h2, dot4(W01, h1, dot4(W00, h0, 0.f))));
        float g1 = dot4(W13, h3, dot4(W12, h2, dot4(W11, h1, dot4(W10, h0, 0.f))));
        float g2 = dot4(W23, h3, dot4(W22, h2, dot4(W21, h1, dot4(W20, h0, 0.f))));
        float g3 = dot4(W33, h3, dot4(W32, h2, dot4(W31, h1, dot4(W30, h0, 0.f))));

        g0 = dpp_xor2_add(dpp_xor1_add(g0));
        g1 = dpp_xor2_add(dpp_xor1_add(g1));
        g2 = dpp_xor2_add(dpp_xor1_add(g2));
        g3 = dpp_xor2_add(dpp_xor1_add(g3));

        const float4 xv = *(const float4*)xp;
        g0 += dot4(I0, xv, b0);
        g1 += dot4(I1, xv, b1);
        g2 += dot4(I2, xv, b2g);
        g3 += dot4(I3, xv, b3);

        const float ig = sigmoid_fast(g0);
        const float fg = sigmoid_fast(g1);
        const float gg = tanh_fast(g2);
        const float og = sigmoid_fast(g3);
        c = fmaf(fg, c, ig * gg);
        const float h = og * tanh_fast(c);

        if (p == 0) {
            hbuf[(s & 1) ^ 1][u] = h;
            *outp = h;
        }
        outp += ostep;
        xp   += xstep;
        __syncthreads();
    }
}

// ---------------- Layer 2: unidirectional, input dim 128, + FC ----------------
// grid = BATCH blocks, 512 threads (8 waves). Unit u = (tid>>6)*8 + ((tid&63)>>3),
// slice p8 = tid&7 owns k-slices of 8 (recurrent) / 16 (input).
// Reduce: DPP xor1/xor2 + ds_swizzle xor4.
__global__ __launch_bounds__(512, 2)
void lstm_layer2(const float* __restrict__ out1,  // [B,T,128]
                 const float* __restrict__ Wih2, const float* __restrict__ Whh2, const float* __restrict__ bias2,
                 const float* __restrict__ Wfc, const float* __restrict__ bfc,
                 float* __restrict__ out)         // [B,1]
{
    const int bidx = blockIdx.x;
    const int tid  = threadIdx.x;
    const int w    = tid >> 6;
    const int lane = tid & 63;
    const int ul   = lane >> 3;
    const int p8   = lane & 7;
    const int u    = w * 8 + ul;
    const int rot  = p8 >> 1;   // bank-conflict-avoiding read rotation

    __shared__ float inbuf[2][CH][2 * HDIM];  // 16 KB
    __shared__ float hbuf[2][HDIM];

    // recurrent weights: row gi*64+u, cols [8p8, 8p8+8)
    const float* whbase = Whh2 + (size_t)u * HDIM + 8 * p8;
    float4 H00 = *(const float4*)(whbase + 0*4096 + 0), H01 = *(const float4*)(whbase + 0*4096 + 4);
    float4 H10 = *(const float4*)(whbase + 1*4096 + 0), H11 = *(const float4*)(whbase + 1*4096 + 4);
    float4 H20 = *(const float4*)(whbase + 2*4096 + 0), H21 = *(const float4*)(whbase + 2*4096 + 4);
    float4 H30 = *(const float4*)(whbase + 3*4096 + 0), H31 = *(const float4*)(whbase + 3*4096 + 4);
    // input weights: row gi*64+u, cols 16p8 + 4*((j+rot)&3), j=0..3
    const float* wibase = Wih2 + (size_t)u * 128 + 16 * p8;
    #define LWI(g, j) *(const float4*)(wibase + (g)*8192 + ((((j) + rot) & 3) << 2))
    float4 X00 = LWI(0,0), X01 = LWI(0,1), X02 = LWI(0,2), X03 = LWI(0,3);
    float4 X10 = LWI(1,0), X11 = LWI(1,1), X12 = LWI(1,2), X13 = LWI(1,3);
    float4 X20 = LWI(2,0), X21 = LWI(2,1), X22 = LWI(2,2), X23 = LWI(2,3);
    float4 X30 = LWI(3,0), X31 = LWI(3,1), X32 = LWI(3,2), X33 = LWI(3,3);
    #undef LWI
    float b0 = bias2[u], b1 = bias2[64 + u], b2g = bias2[128 + u], b3 = bias2[192 + u];
    PIN4(H00); PIN4(H01); PIN4(H10); PIN4(H11);
    PIN4(H20); PIN4(H21); PIN4(H30); PIN4(H31);
    PIN4(X00); PIN4(X01); PIN4(X02); PIN4(X03);
    PIN4(X10); PIN4(X11); PIN4(X12); PIN4(X13);
    PIN4(X20); PIN4(X21); PIN4(X22); PIN4(X23);
    PIN4(X30); PIN4(X31); PIN4(X32); PIN4(X33);
    PIN1(b0); PIN1(b1); PIN1(b2g); PIN1(b3);

    if (tid < 2 * HDIM) ((float*)hbuf)[tid] = 0.f;

    const float4* src = (const float4*)(out1 + (size_t)bidx * TLEN * (2 * HDIM));
    ((float4*)&inbuf[0][0][0])[tid] = src[tid];   // chunk 0: 512 float4
    __syncthreads();

    float c = 0.f;

    for (int chunk = 0; chunk < TLEN / CH; ++chunk) {
        const int cb = chunk & 1;
        const bool havenext = (chunk + 1 < TLEN / CH);
        float4 pf;
        if (havenext) pf = src[(size_t)(chunk + 1) * 512 + tid];

        #pragma unroll 2
        for (int ts = 0; ts < CH; ++ts) {
            const int s = chunk * CH + ts;
            const float* hb = hbuf[s & 1];
            const float* xr = &inbuf[cb][ts][16 * p8];

            const float4 x0 = *(const float4*)(xr + (((0 + rot) & 3) << 2));
            const float4 x1 = *(const float4*)(xr + (((1 + rot) & 3) << 2));
            const float4 x2 = *(const float4*)(xr + (((2 + rot) & 3) << 2));
            const float4 x3 = *(const float4*)(xr + (((3 + rot) & 3) << 2));
            const float4 h0 = *(const float4*)(hb + 8 * p8 + 0);
            const float4 h1 = *(const float4*)(hb + 8 * p8 + 4);

            float g0 = dot4(H01, h1, dot4(H00, h0, dot4(X03, x3, dot4(X02, x2, dot4(X01, x1, dot4(X00, x0, 0.f))))));
            float g1 = dot4(H11, h1, dot4(H10, h0, dot4(X13, x3, dot4(X12, x2, dot4(X11, x1, dot4(X10, x0, 0.f))))));
            float g2 = dot4(H21, h1, dot4(H20, h0, dot4(X23, x3, dot4(X22, x2, dot4(X21, x1, dot4(X20, x0, 0.f))))));
            float g3 = dot4(H31, h1, dot4(H30, h0, dot4(X33, x3, dot4(X32, x2, dot4(X31, x1, dot4(X30, x0, 0.f))))));

            g0 = swz_xor4_add(dpp_xor2_add(dpp_xor1_add(g0))) + b0;
            g1 = swz_xor4_add(dpp_xor2_add(dpp_xor1_add(g1))) + b1;
            g2 = swz_xor4_add(dpp_xor2_add(dpp_xor1_add(g2))) + b2g;
            g3 = swz_xor4_add(dpp_xor2_add(dpp_xor1_add(g3))) + b3;

            const float ig = sigmoid_fast(g0);
            const float fg = sigmoid_fast(g1);
            const float gg = tanh_fast(g2);
            const float og = sigmoid_fast(g3);
            c = fmaf(fg, c, ig * gg);
            const float h = og * tanh_fast(c);

            if (p8 == 0) hbuf[(s & 1) ^ 1][u] = h;
            __syncthreads();
        }
        if (havenext) {
            ((float4*)&inbuf[cb ^ 1][0][0])[tid] = pf;
            __syncthreads();
        }
    }

    // final h (T even) is in hbuf[0]; FC
    if (w == 0) {
        float part = hbuf[0][lane] * Wfc[lane];
        #pragma unroll
        for (int m = 1; m < 64; m <<= 1) part += __shfl_xor(part, m, 64);
        if (lane == 0) out[bidx] = part + bfc[0];
    }
}

extern "C" void kernel_launch(void* const* d_in, const int* in_sizes, int n_in,
                              void* d_out, int out_size, void* d_ws, size_t ws_size,
                              hipStream_t stream) {
    const float* x     = (const float*)d_in[0];
    const float* Wih_f = (const float*)d_in[1];
    const float* Whh_f = (const float*)d_in[2];
    const float* b_f   = (const float*)d_in[3];
    const float* Wih_b = (const float*)d_in[4];
    const float* Whh_b = (const float*)d_in[5];
    const float* b_b   = (const float*)d_in[6];
    const float* Wih2  = (const float*)d_in[7];
    const float* Whh2  = (const float*)d_in[8];
    const float* b2    = (const float*)d_in[9];
    const float* Wfc   = (const float*)d_in[10];
    const float* bfc   = (const float*)d_in[11];

    float* out1 = (float*)d_ws;  // [B,T,2H] fp32 (256 MiB workspace)

    lstm_layer1<<<dim3(2 * BATCH), dim3(256), 0, stream>>>(
        x, Wih_f, Whh_f, b_f, Wih_b, Whh_b, b_b, out1);
    lstm_layer2<<<dim3(BATCH), dim3(512), 0, stream>>>(
        out1, Wih2, Whh2, b2, Wfc, bfc, (float*)d_out);
}

// Round 4
// 2117.704 us; speedup vs baseline: 1.1285x; 1.1285x over previous
//
#include <hip/hip_runtime.h>

#define HDIM 64
#define BATCH 256
#define TLEN 2048
#define CH 16   // layer-2 streaming chunk (steps)

__device__ __forceinline__ float rcp_fast(float x) { return __builtin_amdgcn_rcpf(x); }
__device__ __forceinline__ float sigmoid_fast(float x) { return rcp_fast(1.0f + __expf(-x)); }
__device__ __forceinline__ float tanh_fast(float x)    { return 1.0f - 2.0f * rcp_fast(1.0f + __expf(2.0f * x)); }

// quad_perm DPP adds: lane^1 and lane^2 (VALU, no LDS pipe)
__device__ __forceinline__ float dpp_xor1_add(float x) {
    int v = __builtin_amdgcn_update_dpp(0, __float_as_int(x), 0xB1, 0xF, 0xF, true);
    return x + __int_as_float(v);
}
__device__ __forceinline__ float dpp_xor2_add(float x) {
    int v = __builtin_amdgcn_update_dpp(0, __float_as_int(x), 0x4E, 0xF, 0xF, true);
    return x + __int_as_float(v);
}
__device__ __forceinline__ float swz_xor4_add(float x) {
    int v = __builtin_amdgcn_ds_swizzle(__float_as_int(x), 0x101F); // xor-4 butterfly
    return x + __int_as_float(v);
}

// Dot-product FMA as inline asm with "v" constraints: forces the weight values
// into arch-VGPRs for their entire live range (defeats the compiler's
// AGPR-park + per-use-copy pattern seen in rounds 2/3) and guarantees one
// VOP2 v_fmac_f32 per MAC.
__device__ __forceinline__ void fmac4(float& acc, const float4 a, const float4 b) {
    asm("v_fmac_f32 %0, %1, %5\n\t"
        "v_fmac_f32 %0, %2, %6\n\t"
        "v_fmac_f32 %0, %3, %7\n\t"
        "v_fmac_f32 %0, %4, %8"
        : "+v"(acc)
        : "v"(a.x), "v"(a.y), "v"(a.z), "v"(a.w),
          "v"(b.x), "v"(b.y), "v"(b.z), "v"(b.w));
}

// ---------------- Layer 1: bidirectional, input dim 4 ----------------
// grid = 2*BATCH blocks, 256 threads. Quad owns unit u = tid>>2; lane p = tid&3
// owns k-slice of 16. Weights in VGPRs via asm fmac, quad-DPP reduce.
__global__ __launch_bounds__(256, 2)
void lstm_layer1(const float* __restrict__ x,      // [B,T,4]
                 const float* __restrict__ Wih_f, const float* __restrict__ Whh_f, const float* __restrict__ b_f,
                 const float* __restrict__ Wih_b, const float* __restrict__ Whh_b, const float* __restrict__ b_b,
                 float* __restrict__ out1)         // [B,T,2H]
{
    const int bidx = blockIdx.x >> 1;
    const int dir  = blockIdx.x & 1;
    const float* __restrict__ Wih = dir ? Wih_b : Wih_f;
    const float* __restrict__ Whh = dir ? Whh_b : Whh_f;
    const float* __restrict__ bb  = dir ? b_b   : b_f;

    const int tid = threadIdx.x;
    const int u   = tid >> 2;
    const int p   = tid & 3;

    __shared__ float xlds[TLEN * 4];    // 32 KB
    __shared__ float hbuf[2][HDIM];

    {   // preload x[b] (2048 float4)
        const float4* src = (const float4*)(x + (size_t)bidx * TLEN * 4);
        float4* dst = (float4*)xlds;
        #pragma unroll
        for (int i = 0; i < 8; ++i) dst[tid + 256 * i] = src[tid + 256 * i];
    }
    if (tid < 2 * HDIM) ((float*)hbuf)[tid] = 0.f;

    // recurrent weights: row gi*64+u, cols [16p,16p+16)
    const float* wbase = Whh + (size_t)u * HDIM + 16 * p;
    const float4 W00 = *(const float4*)(wbase + 0*4096 +  0), W01 = *(const float4*)(wbase + 0*4096 +  4),
                 W02 = *(const float4*)(wbase + 0*4096 +  8), W03 = *(const float4*)(wbase + 0*4096 + 12);
    const float4 W10 = *(const float4*)(wbase + 1*4096 +  0), W11 = *(const float4*)(wbase + 1*4096 +  4),
                 W12 = *(const float4*)(wbase + 1*4096 +  8), W13 = *(const float4*)(wbase + 1*4096 + 12);
    const float4 W20 = *(const float4*)(wbase + 2*4096 +  0), W21 = *(const float4*)(wbase + 2*4096 +  4),
                 W22 = *(const float4*)(wbase + 2*4096 +  8), W23 = *(const float4*)(wbase + 2*4096 + 12);
    const float4 W30 = *(const float4*)(wbase + 3*4096 +  0), W31 = *(const float4*)(wbase + 3*4096 +  4),
                 W32 = *(const float4*)(wbase + 3*4096 +  8), W33 = *(const float4*)(wbase + 3*4096 + 12);
    const float4 I0 = *(const float4*)(Wih + (0*64 + u) * 4);
    const float4 I1 = *(const float4*)(Wih + (1*64 + u) * 4);
    const float4 I2 = *(const float4*)(Wih + (2*64 + u) * 4);
    const float4 I3 = *(const float4*)(Wih + (3*64 + u) * 4);
    const float b0 = bb[u], b1 = bb[64 + u], b2g = bb[128 + u], b3 = bb[192 + u];
    __syncthreads();

    float c = 0.f;
    const float* xp = xlds + (dir ? (TLEN - 1) * 4 : 0);
    const int xstep = dir ? -4 : 4;
    float* outp = out1 + (size_t)bidx * TLEN * (2 * HDIM)
                + (size_t)(dir ? (TLEN - 1) : 0) * (2 * HDIM) + dir * HDIM + u;
    const ptrdiff_t ostep = dir ? -(2 * HDIM) : (2 * HDIM);

    #pragma unroll 2
    for (int s = 0; s < TLEN; ++s) {
        const float* hb = hbuf[s & 1];
        const float4 h0 = *(const float4*)(hb + 16 * p + 0);
        const float4 h1 = *(const float4*)(hb + 16 * p + 4);
        const float4 h2 = *(const float4*)(hb + 16 * p + 8);
        const float4 h3 = *(const float4*)(hb + 16 * p + 12);

        float g0 = 0.f, g1 = 0.f, g2 = 0.f, g3 = 0.f;
        fmac4(g0, W00, h0); fmac4(g0, W01, h1); fmac4(g0, W02, h2); fmac4(g0, W03, h3);
        fmac4(g1, W10, h0); fmac4(g1, W11, h1); fmac4(g1, W12, h2); fmac4(g1, W13, h3);
        fmac4(g2, W20, h0); fmac4(g2, W21, h1); fmac4(g2, W22, h2); fmac4(g2, W23, h3);
        fmac4(g3, W30, h0); fmac4(g3, W31, h1); fmac4(g3, W32, h2); fmac4(g3, W33, h3);

        g0 = dpp_xor2_add(dpp_xor1_add(g0));
        g1 = dpp_xor2_add(dpp_xor1_add(g1));
        g2 = dpp_xor2_add(dpp_xor1_add(g2));
        g3 = dpp_xor2_add(dpp_xor1_add(g3));

        const float4 xv = *(const float4*)xp;
        g0 += b0; fmac4(g0, I0, xv);
        g1 += b1; fmac4(g1, I1, xv);
        g2 += b2g; fmac4(g2, I2, xv);
        g3 += b3; fmac4(g3, I3, xv);

        const float ig = sigmoid_fast(g0);
        const float fg = sigmoid_fast(g1);
        const float gg = tanh_fast(g2);
        const float og = sigmoid_fast(g3);
        c = fmaf(fg, c, ig * gg);
        const float h = og * tanh_fast(c);

        if (p == 0) {
            hbuf[(s & 1) ^ 1][u] = h;
            *outp = h;
        }
        outp += ostep;
        xp   += xstep;
        __syncthreads();
    }
}

// ---------------- Layer 2: unidirectional, input dim 128, + FC ----------------
// grid = BATCH blocks, 512 threads (8 waves). Unit u = (tid>>6)*8 + ((tid&63)>>3),
// slice p8 = tid&7 owns k-slices of 8 (recurrent) / 16 (input).
// Reduce: DPP xor1/xor2 + ds_swizzle xor4.
__global__ __launch_bounds__(512, 2)
void lstm_layer2(const float* __restrict__ out1,  // [B,T,128]
                 const float* __restrict__ Wih2, const float* __restrict__ Whh2, const float* __restrict__ bias2,
                 const float* __restrict__ Wfc, const float* __restrict__ bfc,
                 float* __restrict__ out)         // [B,1]
{
    const int bidx = blockIdx.x;
    const int tid  = threadIdx.x;
    const int w    = tid >> 6;
    const int lane = tid & 63;
    const int ul   = lane >> 3;
    const int p8   = lane & 7;
    const int u    = w * 8 + ul;
    const int rot  = p8 >> 1;   // bank-conflict-avoiding read rotation

    __shared__ float inbuf[2][CH][2 * HDIM];  // 16 KB
    __shared__ float hbuf[2][HDIM];

    // recurrent weights: row gi*64+u, cols [8p8, 8p8+8)
    const float* whbase = Whh2 + (size_t)u * HDIM + 8 * p8;
    const float4 H00 = *(const float4*)(whbase + 0*4096 + 0), H01 = *(const float4*)(whbase + 0*4096 + 4);
    const float4 H10 = *(const float4*)(whbase + 1*4096 + 0), H11 = *(const float4*)(whbase + 1*4096 + 4);
    const float4 H20 = *(const float4*)(whbase + 2*4096 + 0), H21 = *(const float4*)(whbase + 2*4096 + 4);
    const float4 H30 = *(const float4*)(whbase + 3*4096 + 0), H31 = *(const float4*)(whbase + 3*4096 + 4);
    // input weights: row gi*64+u, cols 16p8 + 4*((j+rot)&3), j=0..3
    const float* wibase = Wih2 + (size_t)u * 128 + 16 * p8;
    #define LWI(g, j) *(const float4*)(wibase + (g)*8192 + ((((j) + rot) & 3) << 2))
    const float4 X00 = LWI(0,0), X01 = LWI(0,1), X02 = LWI(0,2), X03 = LWI(0,3);
    const float4 X10 = LWI(1,0), X11 = LWI(1,1), X12 = LWI(1,2), X13 = LWI(1,3);
    const float4 X20 = LWI(2,0), X21 = LWI(2,1), X22 = LWI(2,2), X23 = LWI(2,3);
    const float4 X30 = LWI(3,0), X31 = LWI(3,1), X32 = LWI(3,2), X33 = LWI(3,3);
    #undef LWI
    const float b0 = bias2[u], b1 = bias2[64 + u], b2g = bias2[128 + u], b3 = bias2[192 + u];

    if (tid < 2 * HDIM) ((float*)hbuf)[tid] = 0.f;

    const float4* src = (const float4*)(out1 + (size_t)bidx * TLEN * (2 * HDIM));
    ((float4*)&inbuf[0][0][0])[tid] = src[tid];   // chunk 0: 512 float4
    __syncthreads();

    float c = 0.f;

    for (int chunk = 0; chunk < TLEN / CH; ++chunk) {
        const int cb = chunk & 1;
        const bool havenext = (chunk + 1 < TLEN / CH);
        float4 pf;
        if (havenext) pf = src[(size_t)(chunk + 1) * 512 + tid];

        #pragma unroll 2
        for (int ts = 0; ts < CH; ++ts) {
            const int s = chunk * CH + ts;
            const float* hb = hbuf[s & 1];
            const float* xr = &inbuf[cb][ts][16 * p8];

            const float4 x0 = *(const float4*)(xr + (((0 + rot) & 3) << 2));
            const float4 x1 = *(const float4*)(xr + (((1 + rot) & 3) << 2));
            const float4 x2 = *(const float4*)(xr + (((2 + rot) & 3) << 2));
            const float4 x3 = *(const float4*)(xr + (((3 + rot) & 3) << 2));
            const float4 h0 = *(const float4*)(hb + 8 * p8 + 0);
            const float4 h1 = *(const float4*)(hb + 8 * p8 + 4);

            float g0 = 0.f, g1 = 0.f, g2 = 0.f, g3 = 0.f;
            fmac4(g0, X00, x0); fmac4(g0, X01, x1); fmac4(g0, X02, x2); fmac4(g0, X03, x3);
            fmac4(g0, H00, h0); fmac4(g0, H01, h1);
            fmac4(g1, X10, x0); fmac4(g1, X11, x1); fmac4(g1, X12, x2); fmac4(g1, X13, x3);
            fmac4(g1, H10, h0); fmac4(g1, H11, h1);
            fmac4(g2, X20, x0); fmac4(g2, X21, x1); fmac4(g2, X22, x2); fmac4(g2, X23, x3);
            fmac4(g2, H20, h0); fmac4(g2, H21, h1);
            fmac4(g3, X30, x0); fmac4(g3, X31, x1); fmac4(g3, X32, x2); fmac4(g3, X33, x3);
            fmac4(g3, H30, h0); fmac4(g3, H31, h1);

            g0 = swz_xor4_add(dpp_xor2_add(dpp_xor1_add(g0))) + b0;
            g1 = swz_xor4_add(dpp_xor2_add(dpp_xor1_add(g1))) + b1;
            g2 = swz_xor4_add(dpp_xor2_add(dpp_xor1_add(g2))) + b2g;
            g3 = swz_xor4_add(dpp_xor2_add(dpp_xor1_add(g3))) + b3;

            const float ig = sigmoid_fast(g0);
            const float fg = sigmoid_fast(g1);
            const float gg = tanh_fast(g2);
            const float og = sigmoid_fast(g3);
            c = fmaf(fg, c, ig * gg);
            const float h = og * tanh_fast(c);

            if (p8 == 0) hbuf[(s & 1) ^ 1][u] = h;
            __syncthreads();
        }
        if (havenext) {
            ((float4*)&inbuf[cb ^ 1][0][0])[tid] = pf;
            __syncthreads();
        }
    }

    // final h (T even) is in hbuf[0]; FC
    if (w == 0) {
        float part = hbuf[0][lane] * Wfc[lane];
        #pragma unroll
        for (int m = 1; m < 64; m <<= 1) part += __shfl_xor(part, m, 64);
        if (lane == 0) out[bidx] = part + bfc[0];
    }
}

extern "C" void kernel_launch(void* const* d_in, const int* in_sizes, int n_in,
                              void* d_out, int out_size, void* d_ws, size_t ws_size,
                              hipStream_t stream) {
    const float* x     = (const float*)d_in[0];
    const float* Wih_f = (const float*)d_in[1];
    const float* Whh_f = (const float*)d_in[2];
    const float* b_f   = (const float*)d_in[3];
    const float* Wih_b = (const float*)d_in[4];
    const float* Whh_b = (const float*)d_in[5];
    const float* b_b   = (const float*)d_in[6];
    const float* Wih2  = (const float*)d_in[7];
    const float* Whh2  = (const float*)d_in[8];
    const float* b2    = (const float*)d_in[9];
    const float* Wfc   = (const float*)d_in[10];
    const float* bfc   = (const float*)d_in[11];

    float* out1 = (float*)d_ws;  // [B,T,2H] fp32 (268 MB of workspace; proven available)

    lstm_layer1<<<dim3(2 * BATCH), dim3(256), 0, stream>>>(
        x, Wih_f, Whh_f, b_f, Wih_b, Whh_b, b_b, out1);
    lstm_layer2<<<dim3(BATCH), dim3(512), 0, stream>>>(
        out1, Wih2, Whh2, b2, Wfc, bfc, (float*)d_out);
}